// Round 15
// baseline (138.428 us; speedup 1.0000x reference)
//
#include <hip/hip_runtime.h>
#include <hip/hip_bf16.h>
#include <math.h>

// Problem constants
#define M_ 16
#define N_ 4096
#define D_ 128
#define P_ 8192
#define H_ 32

// Projection tiling
#define NIC 32
#define ICH (N_/NIC)
#define NCB 16            // 256-column blocks, 1 col/thread

// Attention chunking
#define CHUNK 64
#define NCH (P_/CHUNK)    // 128 cache chunks
#define NCH1 (NCH+1)      // +1 for the 16 appended rows

// Workspace layout (float offsets). opart is bf16.
#define QKV_SZ       (3*H_*M_*D_)
#define PART_OFF     (QKV_SZ)
#define OPART_OFF    (QKV_SZ)
#define OPART_HALFSZ ((H_*NCH1*M_*D_)/2)
#define ML_OFF       (OPART_OFF + OPART_HALFSZ)

// ---------------------------------------------------------------------------
// Kernel 1: partial QKV projection. grid (NCB, NIC, 3), block 256. (as r13)
// ---------------------------------------------------------------------------
__global__ __launch_bounds__(256) void k_proj(const float* __restrict__ X,
                                              const float* __restrict__ Wq,
                                              const float* __restrict__ Wk,
                                              const float* __restrict__ Wv,
                                              float* __restrict__ part) {
  const int mat = blockIdx.z;
  const float* __restrict__ W = (mat == 0) ? Wq : ((mat == 1) ? Wk : Wv);
  const int cb = blockIdx.x, ic = blockIdx.y;
  const int t = threadIdx.x;
  const int j0 = cb * 256 + t;
  const int i0 = ic * ICH;

  __shared__ __align__(16) float XT[ICH][20];

  {
    const int i_l = t & 127, mh = t >> 7;
#pragma unroll
    for (int r = 0; r < 8; ++r)
      XT[i_l][mh * 8 + r] = X[(size_t)(mh * 8 + r) * N_ + i0 + i_l];
  }
  __syncthreads();

  float acc[16];
#pragma unroll
  for (int m = 0; m < 16; ++m) acc[m] = 0.f;

#pragma unroll 8
  for (int i = 0; i < ICH; ++i) {
    const float wv = __builtin_nontemporal_load(W + (size_t)(i0 + i) * N_ + j0);
    float xr[16];
    {
      float4 xv;
      xv = *reinterpret_cast<const float4*>(&XT[i][0]);
      xr[0] = xv.x; xr[1] = xv.y; xr[2] = xv.z; xr[3] = xv.w;
      xv = *reinterpret_cast<const float4*>(&XT[i][4]);
      xr[4] = xv.x; xr[5] = xv.y; xr[6] = xv.z; xr[7] = xv.w;
      xv = *reinterpret_cast<const float4*>(&XT[i][8]);
      xr[8] = xv.x; xr[9] = xv.y; xr[10] = xv.z; xr[11] = xv.w;
      xv = *reinterpret_cast<const float4*>(&XT[i][12]);
      xr[12] = xv.x; xr[13] = xv.y; xr[14] = xv.z; xr[15] = xv.w;
    }
#pragma unroll
    for (int m = 0; m < 16; ++m) acc[m] = fmaf(xr[m], wv, acc[m]);
  }

#pragma unroll
  for (int m = 0; m < 16; ++m)
    __builtin_nontemporal_store(acc[m], part + (size_t)((mat * NIC + ic) * M_ + m) * N_ + j0);
}

// ---------------------------------------------------------------------------
// Kernel 2: reduce partials, RMS-norm q/k, relayout. (as r13)
// ---------------------------------------------------------------------------
__global__ __launch_bounds__(256) void k_reduce(const float* __restrict__ part,
                                                float* __restrict__ qkv) {
  const int mat = blockIdx.z, m = blockIdx.y, nc = blockIdx.x;
  const int t = threadIdx.x;
  const int n = nc * 256 + t;

  float s = 0.f;
#pragma unroll
  for (int ic = 0; ic < NIC; ++ic)
    s += __builtin_nontemporal_load(part + (size_t)((mat * NIC + ic) * M_ + m) * N_ + n);

  float ss = s * s;
#pragma unroll
  for (int off = 1; off < 64; off <<= 1) ss += __shfl_xor(ss, off);
  __shared__ float wsum[4];
  const int wave = t >> 6, lane = t & 63;
  if (lane == 0) wsum[wave] = ss;
  __syncthreads();
  const int half = t >> 7;
  const float tot = wsum[half * 2] + wsum[half * 2 + 1];
  const float scale = (mat < 2) ? rsqrtf(tot * (1.0f / 128.0f)) : 1.0f;

  const int h = n >> 7, d = n & 127;
  qkv[(size_t)((mat * H_ + h) * M_ + m) * D_ + d] = s * scale;
}

// ---------------------------------------------------------------------------
// fold8: reduce a[0..7] over the 8 dq-lanes (lane bits 0..2).
// ---------------------------------------------------------------------------
__device__ __forceinline__ float fold8(float a[8], int dq) {
#pragma unroll
  for (int i = 0; i < 4; ++i) {
    const float send = (dq & 4) ? a[i] : a[i + 4];
    const float recv = __shfl_xor(send, 4);
    a[i] = ((dq & 4) ? a[i + 4] : a[i]) + recv;
  }
#pragma unroll
  for (int i = 0; i < 2; ++i) {
    const float send = (dq & 2) ? a[i] : a[i + 2];
    const float recv = __shfl_xor(send, 2);
    a[i] = ((dq & 2) ? a[i + 2] : a[i]) + recv;
  }
  {
    const float send = (dq & 1) ? a[0] : a[1];
    const float recv = __shfl_xor(send, 1);
    a[0] = ((dq & 1) ? a[1] : a[0]) + recv;
  }
  return a[0];
}

__device__ __forceinline__ unsigned pk2(float a, float b) {
  __hip_bfloat16 ha = __float2bfloat16(a), hb = __float2bfloat16(b);
  const unsigned short ua = *reinterpret_cast<unsigned short*>(&ha);
  const unsigned short ub = *reinterpret_cast<unsigned short*>(&hb);
  return (unsigned)ua | ((unsigned)ub << 16);
}

// ---------------------------------------------------------------------------
// Kernel 3: p-split attention — UNFENCED experiment.
// IDENTICAL arithmetic to r14 (passed, absmax 0.0156) with two deltas:
//  (a) ALL __builtin_amdgcn_sched_barrier(0) removed. They were an r9-era
//      spill fix, but sched_barrier(0) forbids ANY instruction motion across
//      it — each mi's 4 ds_read_b128 (~60-120cy) could not overlap adjacent
//      FMAs, serializing scores ~8x150cy/batch (the m141 failure mode).
//      r14's small batches cluster at most ~32 transient b128 -> demand
//      ~110 VGPR, safe under a 128 cap without fences.
//  (b) amdgpu_waves_per_eu(2, 8): cap 256/2... i.e. VGPR cap 128 (r14's
//      min=4 capped at 64; with fences gone live ranges lengthen and a
//      64-cap would spill). Occupancy proved irrelevant (r13 20% vs r14
//      38%, same dur) so min 2 loses nothing.
// ---------------------------------------------------------------------------
__global__ __attribute__((amdgpu_waves_per_eu(2, 8)))
__launch_bounds__(256) void k_attn(const float* __restrict__ cacheK,
                                   const float* __restrict__ cacheV,
                                   const float* __restrict__ qkv,
                                   __hip_bfloat16* __restrict__ opart,
                                   float* __restrict__ ml) {
  const int c = blockIdx.x, h = blockIdx.y;
  const int t = threadIdx.x;
  const int wave = t >> 6, lane = t & 63;
  const int valid = (c < NCH) ? CHUNK : M_;
  const float* __restrict__ Ksrc = (c < NCH)
      ? (cacheK + ((size_t)h * P_ + (size_t)c * CHUNK) * D_)
      : (qkv + (size_t)((1 * H_ + h) * M_) * D_);
  const float* __restrict__ Vsrc = (c < NCH)
      ? (cacheV + ((size_t)h * P_ + (size_t)c * CHUNK) * D_)
      : (qkv + (size_t)((2 * H_ + h) * M_) * D_);

  __shared__ __align__(16) float smem[4096];    // 16 KB: qs[2048] / obuf[4096]
  __shared__ __align__(16) float wx[4 * 128];   // 2 KB wave-private strips
  __shared__ __align__(16) float mlx[4][8][2];  // per-wave (m, l)

  float* qs = smem;                 // [16][128]
  float* wxp = wx + wave * 128;

  // stage q (16x128)
  {
    const float4* src = reinterpret_cast<const float4*>(qkv + (size_t)(h * M_) * D_);
    reinterpret_cast<float4*>(qs)[t] = src[t];
    reinterpret_cast<float4*>(qs)[t + 256] = src[t + 256];
  }
  __syncthreads();

  const int pg = lane >> 3, dq = lane & 7;
  const int dl = lane * 2;
  const int rg = wave >> 1, mbase = (wave & 1) * 8;
  const int rbase = rg * 32;
  int rc = valid - rbase; rc = (rc < 0) ? 0 : ((rc > 32) ? 32 : rc);
  const int nb = rc >> 3;   // 8-row batches: 0, 2, or 4

  float mrun = -3.0e38f, lrun = 0.f;
  float2 o[8];
#pragma unroll
  for (int mi = 0; mi < 8; ++mi) o[mi] = make_float2(0.f, 0.f);

#pragma unroll 1
  for (int b = 0; b < nb; ++b) {
    const int r0 = rbase + b * 8;

    // ---- K loads FIRST (scores' vmcnt wait covers only these 4) ----
    float4 kk0, kk1, kk2, kk3;
    {
      const float* ka = Ksrc + (size_t)(r0 + pg) * D_ + dq * 4;
      kk0 = *reinterpret_cast<const float4*>(ka);
      kk1 = *reinterpret_cast<const float4*>(ka + 32);
      kk2 = *reinterpret_cast<const float4*>(ka + 64);
      kk3 = *reinterpret_cast<const float4*>(ka + 96);
    }
    // ---- V loads (outstanding through scores + fold + softmax) ----
    float2 vv[8];
#pragma unroll
    for (int j = 0; j < 8; ++j)
      vv[j] = *reinterpret_cast<const float2*>(Vsrc + (size_t)(r0 + j) * D_ + dl);

    // ---- scores: a[mi] = q[mbase+mi] . K[r0+pg] (dq d-slice) ----
    float a[8];
#pragma unroll
    for (int mi = 0; mi < 8; ++mi) {
      const float* qrow = qs + (mbase + mi) * D_ + dq * 4;
      const float4 q0 = *reinterpret_cast<const float4*>(qrow);
      const float4 q1 = *reinterpret_cast<const float4*>(qrow + 32);
      const float4 q2 = *reinterpret_cast<const float4*>(qrow + 64);
      const float4 q3 = *reinterpret_cast<const float4*>(qrow + 96);
      float s;
      s = q0.x * kk0.x;
      s = fmaf(q0.y, kk0.y, s); s = fmaf(q0.z, kk0.z, s); s = fmaf(q0.w, kk0.w, s);
      s = fmaf(q1.x, kk1.x, s); s = fmaf(q1.y, kk1.y, s);
      s = fmaf(q1.z, kk1.z, s); s = fmaf(q1.w, kk1.w, s);
      s = fmaf(q2.x, kk2.x, s); s = fmaf(q2.y, kk2.y, s);
      s = fmaf(q2.z, kk2.z, s); s = fmaf(q2.w, kk2.w, s);
      s = fmaf(q3.x, kk3.x, s); s = fmaf(q3.y, kk3.y, s);
      s = fmaf(q3.z, kk3.z, s); s = fmaf(q3.w, kk3.w, s);
      a[mi] = s;
    }

    // ---- fold + online softmax over the 8 rows (pg lanes, bits 3..5) ----
    const float sA = fold8(a, dq);
    float tmax = sA;
    tmax = fmaxf(tmax, __shfl_xor(tmax, 8));
    tmax = fmaxf(tmax, __shfl_xor(tmax, 16));
    tmax = fmaxf(tmax, __shfl_xor(tmax, 32));
    const float mnew = fmaxf(mrun, tmax);
    const float fc = __expf(mrun - mnew);
    mrun = mnew;
    const float wA = __expf(sA - mnew);
    float rs = wA;
    rs += __shfl_xor(rs, 8); rs += __shfl_xor(rs, 16); rs += __shfl_xor(rs, 32);
    lrun = lrun * fc + rs;

    // publish weights (wave-private strip; same-wave RAW ordered by lgkmcnt)
    wxp[pg * 8 + dq] = wA;

    // ---- rescale o (per-m fc gathered via shfl) ----
#pragma unroll
    for (int mi = 0; mi < 8; ++mi) {
      const float fcm = __shfl(fc, (lane & 56) | mi);
      o[mi].x *= fcm; o[mi].y *= fcm;
    }

    // ---- PV over the 8 rows ----
#pragma unroll
    for (int j = 0; j < 8; ++j) {
      const float4 w0 = *reinterpret_cast<const float4*>(&wxp[j * 8]);
      const float4 w1 = *reinterpret_cast<const float4*>(&wxp[j * 8 + 4]);
      const float2 v = vv[j];
#define PVM(i, wc) o[i].x = fmaf(wc, v.x, o[i].x); o[i].y = fmaf(wc, v.y, o[i].y);
      PVM(0, w0.x) PVM(1, w0.y) PVM(2, w0.z) PVM(3, w0.w)
      PVM(4, w1.x) PVM(5, w1.y) PVM(6, w1.z) PVM(7, w1.w)
#undef PVM
    }
  }

  // ---- merge the 4 wave-partials (obuf aliases dead qs region) ----
  __syncthreads();
  float* obuf = smem;  // [4 waves][8 m][128 d]
#pragma unroll
  for (int mi = 0; mi < 8; ++mi)
    *reinterpret_cast<float2*>(&obuf[wave * 1024 + mi * 128 + dl]) = o[mi];
  if (lane < 8) { mlx[wave][lane][0] = mrun; mlx[wave][lane][1] = lrun; }
  __syncthreads();

  {
    const int mm = t >> 4, seg = t & 15;    // 16 m x 16 segments of 8 d
    const int mh = mm >> 3, mi = mm & 7;    // partials live in waves mh and 2+mh
    const float m0v = mlx[mh][mi][0], m1v = mlx[2 + mh][mi][0];
    const float mstar = fmaxf(m0v, m1v);
    const float e0 = __expf(m0v - mstar), e1 = __expf(m1v - mstar);
    const float T = mlx[mh][mi][1] * e0 + mlx[2 + mh][mi][1] * e1;
    const float4 a0 = *reinterpret_cast<const float4*>(&obuf[mh * 1024 + mi * 128 + seg * 8]);
    const float4 a1 = *reinterpret_cast<const float4*>(&obuf[mh * 1024 + mi * 128 + seg * 8 + 4]);
    const float4 b0 = *reinterpret_cast<const float4*>(&obuf[(2 + mh) * 1024 + mi * 128 + seg * 8]);
    const float4 b1 = *reinterpret_cast<const float4*>(&obuf[(2 + mh) * 1024 + mi * 128 + seg * 8 + 4]);
    float r0 = e0 * a0.x + e1 * b0.x, r1 = e0 * a0.y + e1 * b0.y;
    float r2 = e0 * a0.z + e1 * b0.z, r3 = e0 * a0.w + e1 * b0.w;
    float r4 = e0 * a1.x + e1 * b1.x, r5 = e0 * a1.y + e1 * b1.y;
    float r6 = e0 * a1.z + e1 * b1.z, r7 = e0 * a1.w + e1 * b1.w;
    uint4 pk;
    pk.x = pk2(r0, r1); pk.y = pk2(r2, r3); pk.z = pk2(r4, r5); pk.w = pk2(r6, r7);
    const size_t base = ((size_t)(h * NCH1 + c) * M_ + mm) * D_ + seg * 8;
    *reinterpret_cast<uint4*>(opart + base) = pk;
    if (seg == 0) {
      ml[((size_t)(h * NCH1 + c) * M_ + mm) * 2 + 0] = mstar;
      ml[((size_t)(h * NCH1 + c) * M_ + mm) * 2 + 1] = T;
    }
  }
}

// ---------------------------------------------------------------------------
// Kernel 4: combine 129 chunk partials per (h, m). grid (M_, H_), block 128.
// ---------------------------------------------------------------------------
__global__ __launch_bounds__(128) void k_comb(const __hip_bfloat16* __restrict__ opart,
                                              const float* __restrict__ ml,
                                              float* __restrict__ out) {
  const int m = blockIdx.x, h = blockIdx.y, t = threadIdx.x;
  __shared__ float Ms[NCH1], Ls[NCH1];
  for (int i = t; i < NCH1; i += 128) {
    Ms[i] = ml[((size_t)(h * NCH1 + i) * M_ + m) * 2 + 0];
    Ls[i] = ml[((size_t)(h * NCH1 + i) * M_ + m) * 2 + 1];
  }
  __syncthreads();
  float gM = -3.0e38f;
#pragma unroll 8
  for (int c2 = 0; c2 < NCH1; ++c2) gM = fmaxf(gM, Ms[c2]);

  const __hip_bfloat16* __restrict__ ob =
      opart + (size_t)h * NCH1 * M_ * D_ + (size_t)m * D_ + t;
  float T = 0.f, o0 = 0.f, o1 = 0.f, o2 = 0.f, o3 = 0.f;
#pragma unroll 4
  for (int c2 = 0; c2 < NCH1 - 1; c2 += 4) {
    const float f0 = __expf(Ms[c2 + 0] - gM);
    const float f1 = __expf(Ms[c2 + 1] - gM);
    const float f2 = __expf(Ms[c2 + 2] - gM);
    const float f3 = __expf(Ms[c2 + 3] - gM);
    T = fmaf(Ls[c2 + 0], f0, T); T = fmaf(Ls[c2 + 1], f1, T);
    T = fmaf(Ls[c2 + 2], f2, T); T = fmaf(Ls[c2 + 3], f3, T);
    o0 = fmaf(__bfloat162float(ob[(size_t)(c2 + 0) * M_ * D_]), f0, o0);
    o1 = fmaf(__bfloat162float(ob[(size_t)(c2 + 1) * M_ * D_]), f1, o1);
    o2 = fmaf(__bfloat162float(ob[(size_t)(c2 + 2) * M_ * D_]), f2, o2);
    o3 = fmaf(__bfloat162float(ob[(size_t)(c2 + 3) * M_ * D_]), f3, o3);
  }
  {
    const int c2 = NCH1 - 1;
    const float f = __expf(Ms[c2] - gM);
    T = fmaf(Ls[c2], f, T);
    o0 = fmaf(__bfloat162float(ob[(size_t)c2 * M_ * D_]), f, o0);
  }
  out[(size_t)m * N_ + h * D_ + t] = (o0 + o1 + o2 + o3) / T;
}

// ---------------------------------------------------------------------------
extern "C" void kernel_launch(void* const* d_in, const int* in_sizes, int n_in,
                              void* d_out, int out_size, void* d_ws, size_t ws_size,
                              hipStream_t stream) {
  const float* X  = (const float*)d_in[0];
  const float* Wq = (const float*)d_in[1];
  const float* Wk = (const float*)d_in[2];
  const float* Wv = (const float*)d_in[3];
  const float* cK = (const float*)d_in[4];
  const float* cV = (const float*)d_in[5];
  float* ws    = (float*)d_ws;
  float* qkv   = ws;
  float* part  = ws + PART_OFF;
  __hip_bfloat16* opart = (__hip_bfloat16*)(ws + OPART_OFF);
  float* mlbuf = ws + ML_OFF;
  float* out   = (float*)d_out;

  hipLaunchKernelGGL(k_proj,   dim3(NCB, NIC, 3), dim3(256), 0, stream, X, Wq, Wk, Wv, part);
  hipLaunchKernelGGL(k_reduce, dim3(16, M_, 3),   dim3(256), 0, stream, part, qkv);
  hipLaunchKernelGGL(k_attn,   dim3(NCH1, H_),    dim3(256), 0, stream, cK, cV, qkv, opart, mlbuf);
  hipLaunchKernelGGL(k_comb,   dim3(M_, H_),      dim3(128), 0, stream, opart, mlbuf, out);
}